// Round 8
// baseline (33.534 us; speedup 1.0000x reference)
//
#include <hip/hip_runtime.h>
#include <hip/hip_fp16.h>

// Problem geometry (fixed by the reference)
#define NROWS   32768      // out_features N
#define KTOT    8192       // in_features K
#define KP      1024       // packed bytes per row (each stored as one int32 on device)
#define GROUPS  64         // scale groups per row (K/128)

#define BLK     512        // 8 waves
#define ROWS_PER_BLK 64
#define NBLOCKS (NROWS / ROWS_PER_BLK)   // 512 blocks = 2/CU, all resident

// ---------------------------------------------------------------------------
// Fused single kernel. One block = 64 rows x full K.
//
// LDS: 32 KB sign-symmetric fp16 nibble-LUT for the whole 8192-weight row
//        lut[pos][n] = sum_{i<4} (+-x[4*pos+i]) for n<8;  dot(n>=8) = -dot(n^15)
//      + 16.6 KB scale tile (64 rows x 64 groups, coalesced 16 KB read).
//
// Packed reads: each block reads ONE contiguous 256 KB range (64 rows x 4 KB).
// Scales applied in-register -> direct out[] store. No workspace, no pass 2.
//
// LUT LDS layout (bank-engineered): entry (pos, idx) lives at byte
//   addr = {j[1:0]}<<13 | {l[5:3]}<<10 | {w[1:0],hi}<<7 | {l[2:0]}<<4 | idx<<1
// where pos = 512j + 8l + 2w + hi. Bank bits addr[6:2] = {l[2:0], idx[2:1]}
// -> each ds_read_u16 spreads 64 lanes over ~32 banks (avg ~2-way, free).
// Build side writes the same mapping: posP = (p&~63) | ((p&7)<<3) | ((p>>3)&7),
// 16 B block at posP*16 (single b128 store per pos).
// ---------------------------------------------------------------------------
__device__ __forceinline__ float dot_int4(const int4 v, const int basej,
                                          const ushort* __restrict__ lutU)
{
    union { unsigned int u; __half2 h; } cvt;
    __half2 a2 = __half2(__float2half(0.f), __float2half(0.f));
    const int w0[4] = { v.x, v.y, v.z, v.w };
#pragma unroll
    for (int w = 0; w < 4; ++w) {
        const int b   = w0[w] & 255;
        const int mlo = (b >> 3) & 1;
        const int mhi = (b >> 7) & 1;
        const int ilo = (b ^ (mlo * 15)) & 7;
        const int ihi = ((b >> 4) ^ (mhi * 15)) & 7;
        const int alo = basej + (w << 8) + (ilo << 1);
        const int ahi = basej + (w << 8) + 128 + (ihi << 1);
        const unsigned int lo = *(const ushort*)((const char*)lutU + alo);
        const unsigned int hi = *(const ushort*)((const char*)lutU + ahi);
        cvt.u = (lo | (hi << 16)) ^ ((unsigned int)(mlo << 15) | ((unsigned int)mhi << 31));
        a2 = __hadd2(a2, cvt.h);
    }
    const float2 f = __half22float2(a2);
    return f.x + f.y;
}

__global__ __launch_bounds__(BLK, 4)
void bitlin_fused(const float* __restrict__ x,
                  const int* __restrict__ packed,
                  const float* __restrict__ scales,
                  float* __restrict__ out)
{
    __shared__ ushort lutU[16384];     // 32 KB nibble-LUT
    __shared__ float  s_s[64][65];     // padded scale tile

    const int tid     = threadIdx.x;
    const int rowBase = blockIdx.x * ROWS_PER_BLK;

    // ---- Build LUT: thread t owns pos 4t..4t+3 (x[16t..16t+15], coalesced)
    {
        const float4* xv = (const float4*)x;
        float xs[16];
#pragma unroll
        for (int q = 0; q < 4; ++q) {
            const float4 xq = xv[tid * 4 + q];
            xs[q * 4 + 0] = xq.x; xs[q * 4 + 1] = xq.y;
            xs[q * 4 + 2] = xq.z; xs[q * 4 + 3] = xq.w;
        }
#pragma unroll
        for (int pp = 0; pp < 4; ++pp) {
            const int p = tid * 4 + pp;
            const float x0 = xs[pp*4+0], x1 = xs[pp*4+1],
                        x2 = xs[pp*4+2], x3 = xs[pp*4+3];
            ushort h[8];
            float e = -x0 - x1 - x2 - x3;          // n = 0 (bit3=0 => -x3)
            const float t0 = 2.f*x0, t1 = 2.f*x1, t2 = 2.f*x2;
            h[0] = __half_as_ushort(__float2half_rn(e));
            e += t0; h[1] = __half_as_ushort(__float2half_rn(e));
            e += t1; h[3] = __half_as_ushort(__float2half_rn(e));
            e -= t0; h[2] = __half_as_ushort(__float2half_rn(e));
            e += t2; h[6] = __half_as_ushort(__float2half_rn(e));
            e += t0; h[7] = __half_as_ushort(__float2half_rn(e));
            e -= t1; h[5] = __half_as_ushort(__float2half_rn(e));
            e -= t0; h[4] = __half_as_ushort(__float2half_rn(e));
            const int posP = (p & ~63) | ((p & 7) << 3) | ((p >> 3) & 7);
            uint4 pk;
            pk.x = (unsigned)h[0] | ((unsigned)h[1] << 16);
            pk.y = (unsigned)h[2] | ((unsigned)h[3] << 16);
            pk.z = (unsigned)h[4] | ((unsigned)h[5] << 16);
            pk.w = (unsigned)h[6] | ((unsigned)h[7] << 16);
            *(uint4*)&lutU[posP * 8] = pk;
        }
    }

    // ---- Stage scale tile: 64 rows x 64 groups = 16 KB, fully coalesced
    {
        const float4* s4 = (const float4*)(scales + (size_t)rowBase * GROUPS);
#pragma unroll
        for (int i = 0; i < 2; ++i) {
            const int idx = i * 512 + tid;
            const float4 v = s4[idx];
            const int r = idx >> 4;
            const int c = (idx & 15) * 4;
            s_s[r][c + 0] = v.x;
            s_s[r][c + 1] = v.y;
            s_s[r][c + 2] = v.z;
            s_s[r][c + 3] = v.w;
        }
    }
    __syncthreads();

    const int l    = tid & 63;
    const int wave = tid >> 6;                       // 0..7, owns 8 rows
    const int base_lane = ((l >> 3) << 10) | ((l & 7) << 4);
    const int gcol0 = l >> 2;                        // scale col offset
    const int4* __restrict__ p4 = (const int4*)packed;

    // ---- 2-row compute pipeline with next-pair prefetch (8 int4 in flight)
    int4 cur[8], nxt[8];
    {
        const size_t rb = (size_t)(rowBase + wave * 8) * 256;
#pragma unroll
        for (int j = 0; j < 4; ++j) {
            cur[j]     = p4[rb + j * 64 + l];        // row wave*8+0
            cur[4 + j] = p4[rb + 256 + j * 64 + l];  // row wave*8+1
        }
    }
#pragma unroll
    for (int pr = 0; pr < 4; ++pr) {                 // 4 pairs of rows
        const int row0 = wave * 8 + pr * 2;          // local row of cur[0..3]
        if (pr < 3) {
            const size_t rb = (size_t)(rowBase + row0 + 2) * 256;
#pragma unroll
            for (int j = 0; j < 4; ++j) {
                nxt[j]     = p4[rb + j * 64 + l];
                nxt[4 + j] = p4[rb + 256 + j * 64 + l];
            }
        }
#pragma unroll
        for (int h = 0; h < 2; ++h) {                // the 2 rows of this pair
            const int row = row0 + h;
            float acc = 0.f;
#pragma unroll
            for (int j = 0; j < 4; ++j)
                acc = fmaf(dot_int4(cur[h * 4 + j], base_lane | (j << 13), lutU),
                           s_s[row][16 * j + gcol0], acc);
            // full-wave reduce (each lane holds a partial of this row)
            acc += __shfl_xor(acc, 1);
            acc += __shfl_xor(acc, 2);
            acc += __shfl_xor(acc, 4);
            acc += __shfl_xor(acc, 8);
            acc += __shfl_xor(acc, 16);
            acc += __shfl_xor(acc, 32);
            if (l == 0) out[rowBase + row] = acc;
        }
        if (pr < 3) {
#pragma unroll
            for (int q = 0; q < 8; ++q) cur[q] = nxt[q];
        }
    }
}

extern "C" void kernel_launch(void* const* d_in, const int* in_sizes, int n_in,
                              void* d_out, int out_size, void* d_ws, size_t ws_size,
                              hipStream_t stream)
{
    (void)d_ws; (void)ws_size; (void)n_in; (void)in_sizes; (void)out_size;
    const float* x      = (const float*)d_in[0];
    const int*   packed = (const int*)d_in[1];
    const float* scales = (const float*)d_in[2];

    bitlin_fused<<<dim3(NBLOCKS), dim3(BLK), 0, stream>>>(
        x, packed, scales, (float*)d_out);
}

// Round 9
// 30.258 us; speedup vs baseline: 1.1083x; 1.1083x over previous
//
#include <hip/hip_runtime.h>
#include <hip/hip_fp16.h>

// Problem geometry (fixed by the reference)
#define NROWS   32768      // out_features N
#define KTOT    8192       // in_features K
#define KP      1024       // packed bytes per row (each stored as one int32 on device)
#define GROUPS  64         // scale groups per row (K/128)

// Split-K: 1024-weight slices (512 B/row granule) + sign-symmetric fp16 LUT
#define SLICE_W 1024       // weights per K-slice
#define SLICE_I 128        // int32 elements per slice per row (512 B)
#define NSLICES (KTOT / SLICE_W)        // 8
#define BLK     512        // 8 waves
#define ROWS_PER_BLK 256
#define RCHUNKS (NROWS / ROWS_PER_BLK)  // 128 -> grid 1024 = 4 blocks/CU
#define LUTW    136        // 128 entries + 8 pad (keeps rows 16B-aligned, spreads banks)

// ---------------------------------------------------------------------------
// Pass 1: per-(row, group) UNSCALED partials -> pTh[g*NROWS + r] (__half).
// One block = one 1024-weight K-slice (8 groups) x 256 rows.
// Sign-symmetric fp16 byte-LUT: dot(b) = -dot(b ^ 0xFF), idx<128 stored.
// 34 KB LDS -> 4 blocks/CU. Packed reads: 512 B contiguous per row-slice.
// Inner loop: 1 ds_read_u16 + ~6 VALU per packed byte.
// ---------------------------------------------------------------------------
__global__ __launch_bounds__(BLK, 8)
void bitlin_partials(const float* __restrict__ x,
                     const int* __restrict__ packed,
                     __half* __restrict__ pTh)
{
    __shared__ __align__(16) ushort lutU[SLICE_I * LUTW];   // 34 KB

    const int s     = blockIdx.x & (NSLICES - 1);  // K-slice id (0..7)
    const int chunk = blockIdx.x >> 3;             // row-chunk id (0..127)
    const int tid   = threadIdx.x;

    // ---- Build: thread owns (pos = tid>>2, oct = tid&3 -> idx bits 5,6).
    // 5-bit Gray walk over idx bits 0..4 (1 add per entry); bit7==0 => -x7.
    {
        const int pos = tid >> 2;          // 0..127 (8 weights each)
        const int oct = tid & 3;
        float xs[8];
#pragma unroll
        for (int i = 0; i < 8; ++i) xs[i] = x[s * SLICE_W + pos * 8 + i];
        float e = -xs[0] - xs[1] - xs[2] - xs[3] - xs[4]
                + ((oct & 1) ? xs[5] : -xs[5])
                + ((oct & 2) ? xs[6] : -xs[6])
                - xs[7];
        const float t0 = 2.f*xs[0], t1 = 2.f*xs[1], t2 = 2.f*xs[2],
                    t3 = 2.f*xs[3], t4 = 2.f*xs[4];
        ushort h[32];                      // constant-indexed -> stays in regs
#define HSET(i) h[i] = __half_as_ushort(__float2half_rn(e))
        HSET(0);
        e += t0; HSET(1);  e += t1; HSET(3);  e -= t0; HSET(2);
        e += t2; HSET(6);  e += t0; HSET(7);  e -= t1; HSET(5);  e -= t0; HSET(4);
        e += t3; HSET(12); e += t0; HSET(13); e += t1; HSET(15); e -= t0; HSET(14);
        e -= t2; HSET(10); e += t0; HSET(11); e -= t1; HSET(9);  e -= t0; HSET(8);
        e += t4; HSET(24); e += t0; HSET(25); e += t1; HSET(27); e -= t0; HSET(26);
        e += t2; HSET(30); e += t0; HSET(31); e -= t1; HSET(29); e -= t0; HSET(28);
        e -= t3; HSET(20); e += t0; HSET(21); e += t1; HSET(23); e -= t0; HSET(22);
        e -= t2; HSET(18); e += t0; HSET(19); e -= t1; HSET(17); e -= t0; HSET(16);
#undef HSET
#define PK(a,b) ((unsigned)h[a] | ((unsigned)h[b] << 16))
        uint4* dst = (uint4*)&lutU[pos * LUTW + oct * 32];
        dst[0] = make_uint4(PK( 0, 1), PK( 2, 3), PK( 4, 5), PK( 6, 7));
        dst[1] = make_uint4(PK( 8, 9), PK(10,11), PK(12,13), PK(14,15));
        dst[2] = make_uint4(PK(16,17), PK(18,19), PK(20,21), PK(22,23));
        dst[3] = make_uint4(PK(24,25), PK(26,27), PK(28,29), PK(30,31));
#undef PK
    }
    __syncthreads();

    const int lane = tid & 63;
    const int wave = tid >> 6;        // 0..7, owns 32 rows
    const int sub  = lane & 31;       // which int4 within the 512B row-slice
    const int rsub = lane >> 5;       // row-within-2 per wave-iteration
    const int rowBase = chunk * ROWS_PER_BLK + wave * 32;
    const int g = s * 8 + (sub >> 2); // this lane's scale-group
    const ushort* lrow = &lutU[(sub * 4) * LUTW];

    const int4* __restrict__ p4 = (const int4*)packed;

#pragma unroll 4
    for (int t = 0; t < 16; ++t) {
        const int r = rowBase + t * 2 + rsub;
        // 32 lanes cover one row's 512 B slice; 2 rows per wave-load
        const int4 v = p4[r * (KP / 4) + s * (SLICE_I / 4) + sub];
        const int bb[4] = { v.x & 255, v.y & 255, v.z & 255, v.w & 255 };
        float acc = 0.f;
#pragma unroll
        for (int c = 0; c < 4; ++c) {
            const int b   = bb[c];
            const int m   = b >> 7;                  // 0 or 1
            const int idx = (b ^ (-m)) & 127;        // complement if bit7
            unsigned u = lrow[c * LUTW + idx];
            u ^= (unsigned)(m << 15);                // fp16 sign flip
            acc += __half2float(__ushort_as_half((ushort)u));
        }
        // butterfly over the 4 lanes covering one group (128 weights)
        acc += __shfl_xor(acc, 1);
        acc += __shfl_xor(acc, 2);
        if ((sub & 3) == 0)           // leaders: sub=0,4,..,28 -> groups 8s..8s+7
            pTh[g * NROWS + r] = __float2half_rn(acc);
    }
}

// ---------------------------------------------------------------------------
// Pass 2 (proven Round-4/7 kernel, verbatim): out[r] = sum_g pTh[g*N+r]*sc[r][g]
// Block = 512 threads x 64 rows; coalesced reads; scales staged in padded LDS.
// ---------------------------------------------------------------------------
__global__ __launch_bounds__(512)
void bitlin_scale(const __half* __restrict__ pTh,
                  const float* __restrict__ scales,
                  float* __restrict__ out)
{
    __shared__ float s_s[64][65];    // padded: conflict-free column reads
    __shared__ float s_part[64][9];  // per-(row, wave) partials, padded

    const int tid     = threadIdx.x;
    const int lane    = tid & 63;
    const int wave    = tid >> 6;
    const int rowBase = blockIdx.x * 64;

    const float4* s4 = (const float4*)(scales + (size_t)rowBase * GROUPS);
#pragma unroll
    for (int i = 0; i < 2; ++i) {
        const int idx = i * 512 + tid;
        const float4 v = s4[idx];
        const int r = idx >> 4;
        const int c = (idx & 15) * 4;
        s_s[r][c + 0] = v.x;
        s_s[r][c + 1] = v.y;
        s_s[r][c + 2] = v.z;
        s_s[r][c + 3] = v.w;
    }
    __syncthreads();

    const int r = rowBase + lane;
    float acc = 0.f;
#pragma unroll
    for (int i = 0; i < 8; ++i) {
        const int g = wave * 8 + i;
        acc += __half2float(pTh[(size_t)g * NROWS + r]) * s_s[lane][g];
    }
    s_part[lane][wave] = acc;
    __syncthreads();

    if (wave == 0) {
        float a = 0.f;
#pragma unroll
        for (int w = 0; w < 8; ++w) a += s_part[lane][w];
        out[r] = a;
    }
}

// ---------------------------------------------------------------------------
// Fallback (proven Round-2 path) if ws can't hold the 4.2 MB partial matrix.
// ---------------------------------------------------------------------------
__global__ __launch_bounds__(BLK, 4)
void bitlin_main_atomic(const float* __restrict__ x,
                        const int* __restrict__ packed,
                        const float* __restrict__ scales,
                        float* __restrict__ ws)
{
    __shared__ float lut[32][256];
    const int s     = blockIdx.x & 31;
    const int chunk = blockIdx.x >> 5;
    const int tid   = threadIdx.x;
    {
        const int pos = tid >> 4;
        const int b0  = (tid & 15) << 4;
        float xs[8];
#pragma unroll
        for (int i = 0; i < 8; ++i) xs[i] = x[s * 256 + pos * 8 + i];
#pragma unroll
        for (int b = 0; b < 16; ++b) {
            const int byte = b0 + b;
            float v = 0.f;
#pragma unroll
            for (int i = 0; i < 8; ++i)
                v += ((byte >> i) & 1) ? xs[i] : -xs[i];
            lut[pos][byte] = v;
        }
    }
    __syncthreads();

    const int lane = tid & 63;
    const int wave = tid >> 6;
    const int sub  = lane & 7;
    const int rsub = lane >> 3;
    const int rowBase = chunk * 512 + wave * 64;
    const int4* __restrict__ p4 = (const int4*)packed;

#pragma unroll
    for (int t = 0; t < 8; ++t) {
        const int r = rowBase + t * 8 + rsub;
        const int4 v = p4[r * (KP / 4) + s * 8 + sub];
        const float sc = scales[r * GROUPS + s * 2 + (sub >> 2)];
        const int pos0 = sub * 4;
        float acc = lut[pos0 + 0][v.x & 255]
                  + lut[pos0 + 1][v.y & 255]
                  + lut[pos0 + 2][v.z & 255]
                  + lut[pos0 + 3][v.w & 255];
        acc *= sc;
        acc += __shfl_xor(acc, 1);
        acc += __shfl_xor(acc, 2);
        acc += __shfl_xor(acc, 4);
        if (sub == 0) atomicAdd(&ws[r], acc);
    }
}

__global__ __launch_bounds__(512)
void bitlin_fin(const float* __restrict__ ws, float* __restrict__ out)
{
    const int i = blockIdx.x * blockDim.x + threadIdx.x;
    out[i] = ws[i];
}

extern "C" void kernel_launch(void* const* d_in, const int* in_sizes, int n_in,
                              void* d_out, int out_size, void* d_ws, size_t ws_size,
                              hipStream_t stream)
{
    const float* x      = (const float*)d_in[0];
    const int*   packed = (const int*)d_in[1];
    const float* scales = (const float*)d_in[2];

    const size_t pTh_bytes = (size_t)GROUPS * NROWS * sizeof(__half);  // 4.2 MB

    if (ws_size >= pTh_bytes) {
        __half* pTh = (__half*)d_ws;
        bitlin_partials<<<dim3(NSLICES * RCHUNKS), dim3(BLK), 0, stream>>>(x, packed, pTh);
        bitlin_scale<<<dim3(NROWS / 64), dim3(512), 0, stream>>>(pTh, scales, (float*)d_out);
    } else {
        // fallback: proven Round-2 fused path
        float* ws = (float*)d_ws;
        hipMemsetAsync(ws, 0, NROWS * sizeof(float), stream);
        bitlin_main_atomic<<<dim3(32 * (NROWS / 512)), dim3(BLK), 0, stream>>>(x, packed, scales, ws);
        bitlin_fin<<<dim3(NROWS / 512), dim3(512), 0, stream>>>(ws, (float*)d_out);
    }
}